// Round 12
// baseline (2093.905 us; speedup 1.0000x reference)
//
#include <hip/hip_runtime.h>

// Child-Sum Tree-LSTM, level-synchronous, B=8 L=8192 D=768.
// Per level: 5 fused K=768 GEMM products + LSTM cell epilogue.
//   acc0..2 (i,o,u) = hs @ (0.5*W_iou + U_iou)^T
//   acc3 (fl-pre)   = hl@Wfp^T + hr@Wfh^T,  Wfp = 0.5*W_f + U_f, Wfh = 0.5*W_f
//   acc4 (fr-pre)   = hl@Wfh^T + hr@Wfp^T
// Big levels (M>=4096): kernel A (R4/R6-proven): 128x64 tile, 4 waves,
//   2 blocks/CU, 2-deep gload_lds pipeline, counted vmcnt(9), mb-major XCD.
// Tail levels (M=2048..8): ONE persistent kernel, 256 blocks (1/CU,
//   co-residency guaranteed), software device-scope atomic barrier between
//   levels (graph-capture-safe; hipLaunchCooperativeKernel is not).

typedef _Float16 half8 __attribute__((ext_vector_type(8)));
typedef float f32x4 __attribute__((ext_vector_type(4)));

#define ROWB 1536        // bytes per 768-elem fp16 row
#define NT 24            // 768 / 32
#define BUFA 36864       // kernel A buffer: A 16384 + B 20480
#define BUFT 26624       // tail buffer: A 16384 + B 10240

__device__ __forceinline__ float sigm(float x){ return 1.f/(1.f+__expf(-x)); }
__device__ __forceinline__ float tanhfast(float x){ return 1.f - 2.f/(1.f+__expf(2.f*x)); }

__device__ __forceinline__ void gload16(const void* g, void* l){
  __builtin_amdgcn_global_load_lds((const __attribute__((address_space(1))) void*)g,
                                   (__attribute__((address_space(3))) void*)l, 16, 0, 0);
}

// Bw: 5 mats of 768x768 fp16: [0..2]=0.5*W_iou+U_iou (i,o,u), [3]=Wfp=0.5Wf+Uf, [4]=Wfh=0.5Wf
__global__ void prep_weights(const float* __restrict__ Wiou, const float* __restrict__ Uiou,
                             const float* __restrict__ Wf, const float* __restrict__ Uf,
                             _Float16* __restrict__ Bw, unsigned* __restrict__ barCnt)
{
    if (blockIdx.x == 0 && threadIdx.x == 0) atomicExch(barCnt, 0u);
    const int n1 = 2304 * 768, n2 = n1 + 589824, n3 = n2 + 589824;
    int stride = gridDim.x * blockDim.x;
    for (int idx = blockIdx.x * blockDim.x + threadIdx.x; idx < n3; idx += stride) {
        float v;
        if (idx < n1)      v = __fmaf_rn(0.5f, Wiou[idx], Uiou[idx]);
        else if (idx < n2) { int k = idx - n1; v = __fmaf_rn(0.5f, Wf[k], Uf[k]); }
        else               { int k = idx - n2; v = 0.5f * Wf[k]; }
        Bw[idx] = (_Float16)v;
    }
}

__global__ void cast_leaves(const float* __restrict__ x, _Float16* __restrict__ h, int n8)
{
    int stride = gridDim.x * blockDim.x;
    for (int i = blockIdx.x * blockDim.x + threadIdx.x; i < n8; i += stride) {
        float4 v0 = ((const float4*)x)[2 * i];
        float4 v1 = ((const float4*)x)[2 * i + 1];
        half8 o = { (_Float16)v0.x, (_Float16)v0.y, (_Float16)v0.z, (_Float16)v0.w,
                    (_Float16)v1.x, (_Float16)v1.y, (_Float16)v1.z, (_Float16)v1.w };
        ((half8*)h)[i] = o;
    }
}

// ================= kernel A: big levels (M>=4096) — R4/R6 proven =================
__global__ __launch_bounds__(256, 2) void tree_level(
    const _Float16* __restrict__ Hc, const float* __restrict__ Cc,
    const _Float16* __restrict__ Bw,
    const float* __restrict__ biou, const float* __restrict__ bfv,
    _Float16* __restrict__ Hn, float* __restrict__ Cn,
    int M, int mblocks, int firstLevel)
{
    __shared__ __align__(16) char smem[2 * BUFA];
    const int tid = threadIdx.x;
    const int lane = tid & 63;
    const int w = tid >> 6;        // 0..3
    const int wm = w >> 1;         // 0..1 row-wave (64 rows)
    const int wd = w & 1;          // 0..1 col-wave (32 cols)

    // bijective XCD chunking; mb-major within XCD (H tile L2/L3-served)
    const int nwg = mblocks * 12;
    const int orig = blockIdx.x;
    const int xcd = orig & 7, qx = nwg >> 3, rx = nwg & 7;
    const int v = (xcd < rx ? xcd * (qx + 1) : rx * (qx + 1) + (xcd - rx) * qx) + (orig >> 3);
    const int mb = v / 12;
    const int d0c = v - mb * 12;
    const int mBase = mb * 128;
    const int d0 = d0c * 64;

    // stage sources: 4 A + 5 B per thread
    const int l3 = lane >> 3, j = lane & 7;
    const int jjA = j ^ l3;
    const int rbase = w * 8 + l3;
    unsigned offH[4];
#pragma unroll
    for (int s = 0; s < 4; ++s) {
        int gr = mBase + s * 32 + rbase;
        if (gr >= M) gr = M - 1;
        offH[s] = (unsigned)(2 * gr + (jjA >> 2)) * ROWB + (jjA & 3) * 16;
    }
    const int pB = w * 8 + l3;
    unsigned offWb[5];
#pragma unroll
    for (int t = 0; t < 5; ++t)
        offWb[t] = (unsigned)(t * 768 + d0 + 2 * pB + (jjA >> 2)) * ROWB + (jjA & 3) * 16;
    const int wK = w * 1024;

#define STAGE_A(bi, ko) do { \
    _Pragma("unroll") for (int s = 0; s < 4; ++s) \
        gload16((const char*)Hc + offH[s] + (ko), smem + (bi) * BUFA + s * 4096 + wK); \
    _Pragma("unroll") for (int t = 0; t < 5; ++t) \
        gload16((const char*)Bw + offWb[t] + (ko), smem + (bi) * BUFA + 16384 + t * 4096 + wK); \
} while (0)

    // compute offsets (kt-invariant)
    const int q = lane >> 4;
    const int lr16 = lane & 15;
    int offA[4], offB[2];
#pragma unroll
    for (int fm = 0; fm < 4; ++fm) {
        int r = wm * 64 + fm * 16 + lr16;
        offA[fm] = r * 128 + ((q ^ (r & 7)) * 16);
    }
#pragma unroll
    for (int fd = 0; fd < 2; ++fd) {
        int cl = wd * 32 + fd * 16 + lr16;
        int p = cl >> 1;
        int jb = ((cl & 1) * 4 + q) ^ (p & 7);
        offB[fd] = 16384 + p * 128 + jb * 16;
    }

    f32x4 acc[5][4][2];
#pragma unroll
    for (int g = 0; g < 5; ++g)
#pragma unroll
        for (int a = 0; a < 4; ++a)
#pragma unroll
            for (int b2 = 0; b2 < 2; ++b2)
                acc[g][a][b2] = (f32x4){0.f, 0.f, 0.f, 0.f};

    STAGE_A(0, 0);
    int cur = 0;
    for (int kt = 0; kt < NT; ++kt) {
        if (kt + 1 < NT) {
            STAGE_A(cur ^ 1, (kt + 1) * 64);
            asm volatile("s_waitcnt vmcnt(9)" ::: "memory");
        } else {
            asm volatile("s_waitcnt vmcnt(0)" ::: "memory");
        }
        __builtin_amdgcn_s_barrier();
        __builtin_amdgcn_sched_barrier(0);
        const char* bb = smem + cur * BUFA;
        half8 hl[4], hr[4];
#pragma unroll
        for (int fm = 0; fm < 4; ++fm) {
            hl[fm] = *(const half8*)(bb + offA[fm]);
            hr[fm] = *(const half8*)(bb + (offA[fm] ^ 64));
        }
        __builtin_amdgcn_s_setprio(1);
#pragma unroll
        for (int fd = 0; fd < 2; ++fd) {
            const char* bp = bb + offB[fd];
            half8 b0 = *(const half8*)(bp);
            half8 b1 = *(const half8*)(bp + 4096);
            half8 b2 = *(const half8*)(bp + 8192);
            half8 b3 = *(const half8*)(bp + 12288);   // Wfp
            half8 b4 = *(const half8*)(bp + 16384);   // Wfh
#pragma unroll
            for (int fm = 0; fm < 4; ++fm) {
                half8 hs = hl[fm] + hr[fm];
                acc[0][fm][fd] = __builtin_amdgcn_mfma_f32_16x16x32_f16(hs, b0, acc[0][fm][fd], 0, 0, 0);
                acc[1][fm][fd] = __builtin_amdgcn_mfma_f32_16x16x32_f16(hs, b1, acc[1][fm][fd], 0, 0, 0);
                acc[2][fm][fd] = __builtin_amdgcn_mfma_f32_16x16x32_f16(hs, b2, acc[2][fm][fd], 0, 0, 0);
                acc[3][fm][fd] = __builtin_amdgcn_mfma_f32_16x16x32_f16(hl[fm], b3, acc[3][fm][fd], 0, 0, 0);
                acc[3][fm][fd] = __builtin_amdgcn_mfma_f32_16x16x32_f16(hr[fm], b4, acc[3][fm][fd], 0, 0, 0);
                acc[4][fm][fd] = __builtin_amdgcn_mfma_f32_16x16x32_f16(hl[fm], b4, acc[4][fm][fd], 0, 0, 0);
                acc[4][fm][fd] = __builtin_amdgcn_mfma_f32_16x16x32_f16(hr[fm], b3, acc[4][fm][fd], 0, 0, 0);
            }
        }
        __builtin_amdgcn_s_setprio(0);
        if (kt + 1 < NT) __builtin_amdgcn_s_barrier();
        cur ^= 1;
    }

#pragma unroll
    for (int fd = 0; fd < 2; ++fd) {
        const int col = d0 + wd * 32 + fd * 16 + lr16;
        const float bi = biou[col];
        const float bo = biou[768 + col];
        const float bu = biou[1536 + col];
        const float bf = bfv[col];
#pragma unroll
        for (int fm = 0; fm < 4; ++fm) {
            const int rb = mBase + wm * 64 + fm * 16 + q * 4;
#pragma unroll
            for (int r4 = 0; r4 < 4; ++r4) {
                int row = rb + r4;
                if (row < M) {
                    float iv = acc[0][fm][fd][r4] + bi;
                    float ov = acc[1][fm][fd][r4] + bo;
                    float uv = acc[2][fm][fd][r4] + bu;
                    float fl = sigm(acc[3][fm][fd][r4] + bf);
                    float fr = sigm(acc[4][fm][fd][r4] + bf);
                    float clv = 0.f, crv = 0.f;
                    if (!firstLevel) {
                        clv = Cc[(size_t)(2 * row) * 768 + col];
                        crv = Cc[(size_t)(2 * row + 1) * 768 + col];
                    }
                    float c = sigm(iv) * tanhfast(uv) + fl * clv + fr * crv;
                    float h = sigm(ov) * tanhfast(c);
                    Hn[(size_t)row * 768 + col] = (_Float16)h;
                    Cn[(size_t)row * 768 + col] = c;
                }
            }
        }
    }
}

// ================= tree_tail: persistent, levels M=2048..8 =================
// 256 blocks x 256 thr (1/CU guaranteed co-resident; LDS 53.2KB).
// Software grid barrier: monotonic device-scope atomic counter + per-wave
// __threadfence() release/acquire (L2 wb/inv across XCDs).
__global__ __launch_bounds__(256) void tree_tail(
    const _Float16* __restrict__ Bw,
    const float* __restrict__ biou, const float* __restrict__ bfv,
    _Float16* __restrict__ HcIn, _Float16* __restrict__ HnIn,
    float* __restrict__ CcIn, float* __restrict__ CnIn,
    float* __restrict__ out, unsigned* __restrict__ barCnt)
{
    __shared__ __align__(16) char smem[2 * BUFT];
    const int tid = threadIdx.x;
    const int lane = tid & 63;
    const int w = tid >> 6;
    const int wm = w >> 1;
    const int wd = w & 1;
    const int l3 = lane >> 3, j = lane & 7;
    const int jj0 = j ^ l3;
    const int q = lane >> 4;
    const int lr16 = lane & 15;

    // tile-invariant pieces
    int dstA[4];
#pragma unroll
    for (int s = 0; s < 4; ++s) dstA[s] = (s * 4 + w) * 1024;
    int colW[3], dstB[3];
#pragma unroll
    for (int s = 0; s < 3; ++s) {
        int i = s * 4 + w;
        if (i >= 10) i -= 2;                 // duplicate slots benign
        int t = i >> 1, half = i & 1;
        int p = half * 8 + l3;
        colW[s] = t * 768 + 2 * p + (jj0 >> 2);
        dstB[s] = 16384 + t * 2048 + half * 1024;
    }
    int offA[4];
#pragma unroll
    for (int fm = 0; fm < 4; ++fm) {
        int r = wm * 64 + fm * 16 + lr16;
        offA[fm] = r * 128 + ((q ^ (r & 7)) * 16);
    }
    int offB;
    {
        int cl = wd * 16 + lr16;
        int p = cl >> 1;
        int jb = ((cl & 1) * 4 + q) ^ (p & 7);
        offB = 16384 + p * 128 + jb * 16;
    }

    const _Float16* hc = HcIn; _Float16* hn = HnIn;
    const float* cc = CcIn;    float* cn = CnIn;
    unsigned target = 0;

    for (int M = 2048; M >= 8; M >>= 1) {
        const int mblocks = (M + 127) >> 7;
        const int nact = mblocks * 24;
        for (int t = blockIdx.x; t < nact; t += 256) {
            __syncthreads();                 // prior tile's LDS reads done (WAR)
            const int mb = t / 24;
            const int d0c = t - mb * 24;
            const int mBase = mb * 128;
            const int d0 = d0c * 32;

            unsigned offHa_[4];
#pragma unroll
            for (int s = 0; s < 4; ++s) {
                int gr = mBase + (s * 4 + w) * 8 + l3;
                if (gr >= M) gr = M - 1;
                offHa_[s] = (unsigned)(2 * gr + (jj0 >> 2)) * ROWB + (jj0 & 3) * 16;
            }
            unsigned offWb_[3];
#pragma unroll
            for (int s = 0; s < 3; ++s)
                offWb_[s] = (unsigned)(colW[s] + d0) * ROWB + (jj0 & 3) * 16;

#define STAGE_T(bi_, ko) do { \
    _Pragma("unroll") for (int s = 0; s < 4; ++s) \
        gload16((const char*)hc + offHa_[s] + (ko), smem + (bi_) * BUFT + dstA[s]); \
    _Pragma("unroll") for (int s = 0; s < 3; ++s) \
        gload16((const char*)Bw + offWb_[s] + (ko), smem + (bi_) * BUFT + dstB[s]); \
} while (0)

            f32x4 acc[5][4];
#pragma unroll
            for (int g = 0; g < 5; ++g)
#pragma unroll
                for (int a = 0; a < 4; ++a)
                    acc[g][a] = (f32x4){0.f, 0.f, 0.f, 0.f};

            STAGE_T(0, 0);
            int cur = 0;
            for (int kt = 0; kt < NT; ++kt) {
                if (kt + 1 < NT) {
                    STAGE_T(cur ^ 1, (kt + 1) * 64);
                    asm volatile("s_waitcnt vmcnt(7)" ::: "memory");
                } else {
                    asm volatile("s_waitcnt vmcnt(0)" ::: "memory");
                }
                __builtin_amdgcn_s_barrier();
                __builtin_amdgcn_sched_barrier(0);
                const char* bb = smem + cur * BUFT;
                half8 b0 = *(const half8*)(bb + offB);
                half8 b1 = *(const half8*)(bb + offB + 2048);
                half8 b2 = *(const half8*)(bb + offB + 4096);
                half8 b3 = *(const half8*)(bb + offB + 6144);   // Wfp
                half8 b4 = *(const half8*)(bb + offB + 8192);   // Wfh
                __builtin_amdgcn_s_setprio(1);
#pragma unroll
                for (int fm = 0; fm < 4; ++fm) {
                    half8 hl = *(const half8*)(bb + offA[fm]);
                    half8 hr = *(const half8*)(bb + (offA[fm] ^ 64));
                    acc[3][fm] = __builtin_amdgcn_mfma_f32_16x16x32_f16(hl, b3, acc[3][fm], 0, 0, 0);
                    acc[4][fm] = __builtin_amdgcn_mfma_f32_16x16x32_f16(hl, b4, acc[4][fm], 0, 0, 0);
                    half8 hs = hl + hr;
                    acc[0][fm] = __builtin_amdgcn_mfma_f32_16x16x32_f16(hs, b0, acc[0][fm], 0, 0, 0);
                    acc[1][fm] = __builtin_amdgcn_mfma_f32_16x16x32_f16(hs, b1, acc[1][fm], 0, 0, 0);
                    acc[2][fm] = __builtin_amdgcn_mfma_f32_16x16x32_f16(hs, b2, acc[2][fm], 0, 0, 0);
                    acc[3][fm] = __builtin_amdgcn_mfma_f32_16x16x32_f16(hr, b4, acc[3][fm], 0, 0, 0);
                    acc[4][fm] = __builtin_amdgcn_mfma_f32_16x16x32_f16(hr, b3, acc[4][fm], 0, 0, 0);
                }
                __builtin_amdgcn_s_setprio(0);
                if (kt + 1 < NT) __builtin_amdgcn_s_barrier();
                cur ^= 1;
            }

            const int col = d0 + wd * 16 + lr16;
            const float bi = biou[col];
            const float bo = biou[768 + col];
            const float bu = biou[1536 + col];
            const float bf = bfv[col];
            const int fin = (M == 8);
#pragma unroll
            for (int fm = 0; fm < 4; ++fm) {
                const int rb = mBase + wm * 64 + fm * 16 + q * 4;
#pragma unroll
                for (int r4 = 0; r4 < 4; ++r4) {
                    int row = rb + r4;
                    if (row < M) {
                        float iv = acc[0][fm][r4] + bi;
                        float ov = acc[1][fm][r4] + bo;
                        float uv = acc[2][fm][r4] + bu;
                        float fl = sigm(acc[3][fm][r4] + bf);
                        float fr = sigm(acc[4][fm][r4] + bf);
                        float clv = cc[(size_t)(2 * row) * 768 + col];
                        float crv = cc[(size_t)(2 * row + 1) * 768 + col];
                        float c = sigm(iv) * tanhfast(uv) + fl * clv + fr * crv;
                        float h = sigm(ov) * tanhfast(c);
                        if (fin) {
                            out[row * 768 + col] = h;
                            out[6144 + row * 768 + col] = c;
                        } else {
                            hn[(size_t)row * 768 + col] = (_Float16)h;
                            cn[(size_t)row * 768 + col] = c;
                        }
                    }
                }
            }
        }

        if (M > 8) {
            // grid barrier: release (all waves) -> count -> acquire (all waves)
            __threadfence();
            __syncthreads();
            if (tid == 0) {
                target += 256;
                __hip_atomic_fetch_add(barCnt, 1u, __ATOMIC_RELEASE, __HIP_MEMORY_SCOPE_AGENT);
                while (__hip_atomic_load(barCnt, __ATOMIC_ACQUIRE, __HIP_MEMORY_SCOPE_AGENT) < target)
                    __builtin_amdgcn_s_sleep(2);
            }
            __syncthreads();
            __threadfence();
            const _Float16* th = hc; hc = hn; hn = (_Float16*)th;
            const float* tc = cc; cc = cn; cn = (float*)tc;
        }
    }
}

extern "C" void kernel_launch(void* const* d_in, const int* in_sizes, int n_in,
                              void* d_out, int out_size, void* d_ws, size_t ws_size,
                              hipStream_t stream)
{
    const float* leaf = (const float*)d_in[0];
    const float* Wiou = (const float*)d_in[1];
    const float* biou = (const float*)d_in[2];
    const float* Uiou = (const float*)d_in[3];
    const float* Wf   = (const float*)d_in[4];
    const float* bfv  = (const float*)d_in[5];
    const float* Uf   = (const float*)d_in[6];

    char* ws = (char*)d_ws;
    _Float16* Bw  = (_Float16*)(ws);                 // 5x768x768 fp16 = 5,898,240 B
    unsigned* cnt = (unsigned*)(ws + 5898240);       // barrier counter (256 B pad)
    _Float16* H0  = (_Float16*)(ws + 5898496);       // 65536x768 fp16
    _Float16* H1  = (_Float16*)(ws + 106561792);     // 32768x768 fp16
    float*    C0  = (float*)(ws + 156893440);        // 32768x768 f32
    float*    C1  = (float*)(ws + 257556736);        // 16384x768 f32
    // total ws use: 307,888,384 bytes

    prep_weights<<<1024, 256, 0, stream>>>(Wiou, Uiou, Wf, Uf, Bw, cnt);
    cast_leaves<<<2048, 256, 0, stream>>>(leaf, H0, 50331648 / 8);

    float* out = (float*)d_out;  // [2,8,768]
    _Float16* Hc = H0; _Float16* Hn = H1;
    float* Cc = C1; float* Cn = C0;
    int rows = 65536, level = 0;
    while (rows > 4096) {                            // M = 32768,16384,8192,4096
        int M = rows >> 1;
        int mblocks = M / 128;
        tree_level<<<mblocks * 12, 256, 0, stream>>>(Hc, Cc, Bw, biou, bfv,
            Hn, Cn, M, mblocks, level == 0 ? 1 : 0);
        _Float16* th = Hc; Hc = Hn; Hn = th;
        float* tc = Cc; Cc = Cn; Cn = tc;
        rows = M; ++level;
    }
    // here: Hc==H0, Cc==C1 (M=4096 result); tail does M=2048..8
    tree_tail<<<256, 256, 0, stream>>>(Bw, biou, bfv, Hc, Hn, Cc, Cn, out, cnt);
}

// Round 13
// 1383.606 us; speedup vs baseline: 1.5134x; 1.5134x over previous
//
#include <hip/hip_runtime.h>

// Child-Sum Tree-LSTM, level-synchronous, B=8 L=8192 D=768.
// Per level: 5 fused K=768 GEMM products + LSTM cell epilogue.
//   acc0..2 (i,o,u) = hs @ (0.5*W_iou + U_iou)^T
//   acc3 (fl-pre)   = hl@Wfp^T + hr@Wfh^T,  Wfp = 0.5*W_f + U_f, Wfh = 0.5*W_f
//   acc4 (fr-pre)   = hl@Wfh^T + hr@Wfp^T
// R13: B (weights) LOADED DIRECT-TO-REGISTER from global (L2-resident,
// 16 rows x 64B fully-utilized segments per wave) — LDS holds only A
// (32KB dbuf), staging 4 loads/thread, counted vmcnt(4). B leaves the
// barrier-locked chain; its latency hides under the MFMA burst.
// Big levels (M>=4096): kernel A 128x64, 4 waves, 2 blocks/CU, mb-major XCD.
// Tail levels (M=2048..8): per-level tree_small 128x32, 3 blocks/CU.
// [R12 post-mortem: persistent-kernel software grid barrier = 140us/level
//  — 8x worse than per-level launches; grid fusion abandoned.]

typedef _Float16 half8 __attribute__((ext_vector_type(8)));
typedef float f32x4 __attribute__((ext_vector_type(4)));

#define ROWB 1536        // bytes per 768-elem fp16 row
#define NT 24            // 768 / 32
#define MATB 1179648     // 768*768*2 bytes per weight mat
#define BUFA 16384       // kernel A: A-tile only (128 rows x 128B)
#define BUFT 16384       // tail: A-tile only

__device__ __forceinline__ float sigm(float x){ return 1.f/(1.f+__expf(-x)); }
__device__ __forceinline__ float tanhfast(float x){ return 1.f - 2.f/(1.f+__expf(2.f*x)); }

__device__ __forceinline__ void gload16(const void* g, void* l){
  __builtin_amdgcn_global_load_lds((const __attribute__((address_space(1))) void*)g,
                                   (__attribute__((address_space(3))) void*)l, 16, 0, 0);
}

// Bw: 5 mats of 768x768 fp16: [0..2]=0.5*W_iou+U_iou (i,o,u), [3]=Wfp=0.5Wf+Uf, [4]=Wfh=0.5Wf
__global__ void prep_weights(const float* __restrict__ Wiou, const float* __restrict__ Uiou,
                             const float* __restrict__ Wf, const float* __restrict__ Uf,
                             _Float16* __restrict__ Bw)
{
    const int n1 = 2304 * 768, n2 = n1 + 589824, n3 = n2 + 589824;
    int stride = gridDim.x * blockDim.x;
    for (int idx = blockIdx.x * blockDim.x + threadIdx.x; idx < n3; idx += stride) {
        float v;
        if (idx < n1)      v = __fmaf_rn(0.5f, Wiou[idx], Uiou[idx]);
        else if (idx < n2) { int k = idx - n1; v = __fmaf_rn(0.5f, Wf[k], Uf[k]); }
        else               { int k = idx - n2; v = 0.5f * Wf[k]; }
        Bw[idx] = (_Float16)v;
    }
}

__global__ void cast_leaves(const float* __restrict__ x, _Float16* __restrict__ h, int n8)
{
    int stride = gridDim.x * blockDim.x;
    for (int i = blockIdx.x * blockDim.x + threadIdx.x; i < n8; i += stride) {
        float4 v0 = ((const float4*)x)[2 * i];
        float4 v1 = ((const float4*)x)[2 * i + 1];
        half8 o = { (_Float16)v0.x, (_Float16)v0.y, (_Float16)v0.z, (_Float16)v0.w,
                    (_Float16)v1.x, (_Float16)v1.y, (_Float16)v1.z, (_Float16)v1.w };
        ((half8*)h)[i] = o;
    }
}

// ================= kernel A: big levels (M>=4096) =================
// LDS per buffer: A 128 rows x 128B. Row r chunk j: jj=j^(r&7); side=jj>>2
// (0=HL,1=HR), kchunk=jj&3 of H row 2*(mBase+r)+side.
__global__ __launch_bounds__(256, 2) void tree_level(
    const _Float16* __restrict__ Hc, const float* __restrict__ Cc,
    const _Float16* __restrict__ Bw,
    const float* __restrict__ biou, const float* __restrict__ bfv,
    _Float16* __restrict__ Hn, float* __restrict__ Cn,
    int M, int mblocks, int firstLevel)
{
    __shared__ __align__(16) char smem[2 * BUFA];
    const int tid = threadIdx.x;
    const int lane = tid & 63;
    const int w = tid >> 6;        // 0..3
    const int wm = w >> 1;         // 0..1 row-wave (64 rows)
    const int wd = w & 1;          // 0..1 col-wave (32 cols)

    // bijective XCD chunking; mb-major within XCD (H tile L2/L3-served)
    const int nwg = mblocks * 12;
    const int orig = blockIdx.x;
    const int xcd = orig & 7, qx = nwg >> 3, rx = nwg & 7;
    const int v = (xcd < rx ? xcd * (qx + 1) : rx * (qx + 1) + (xcd - rx) * qx) + (orig >> 3);
    const int mb = v / 12;
    const int d0c = v - mb * 12;
    const int mBase = mb * 128;
    const int d0 = d0c * 64;

    // A stage sources: 4 per thread
    const int l3 = lane >> 3, j = lane & 7;
    const int jjA = j ^ l3;
    const int rbase = w * 8 + l3;
    unsigned offH[4];
#pragma unroll
    for (int s = 0; s < 4; ++s) {
        int gr = mBase + s * 32 + rbase;
        if (gr >= M) gr = M - 1;
        offH[s] = (unsigned)(2 * gr + (jjA >> 2)) * ROWB + (jjA & 3) * 16;
    }
    const int wK = w * 1024;

#define STAGE_A(bi, ko) do { \
    _Pragma("unroll") for (int s = 0; s < 4; ++s) \
        gload16((const char*)Hc + offH[s] + (ko), smem + (bi) * BUFA + s * 4096 + wK); \
} while (0)

    // compute offsets (kt-invariant)
    const int q = lane >> 4;
    const int lr16 = lane & 15;
    int offA[4];
#pragma unroll
    for (int fm = 0; fm < 4; ++fm) {
        int r = wm * 64 + fm * 16 + lr16;
        offA[fm] = r * 128 + ((q ^ (r & 7)) * 16);
    }
    // B direct-to-reg base offsets: row = gate col, 16B chunk = q
    size_t offBg[2];
#pragma unroll
    for (int fd = 0; fd < 2; ++fd) {
        int colOut = d0 + wd * 32 + fd * 16 + lr16;
        offBg[fd] = (size_t)colOut * ROWB + q * 16;
    }

    f32x4 acc[5][4][2];
#pragma unroll
    for (int g = 0; g < 5; ++g)
#pragma unroll
        for (int a = 0; a < 4; ++a)
#pragma unroll
            for (int b2 = 0; b2 < 2; ++b2)
                acc[g][a][b2] = (f32x4){0.f, 0.f, 0.f, 0.f};

    STAGE_A(0, 0);
    int cur = 0;
    for (int kt = 0; kt < NT; ++kt) {
        if (kt + 1 < NT) {
            STAGE_A(cur ^ 1, (kt + 1) * 64);
            asm volatile("s_waitcnt vmcnt(4)" ::: "memory");
        } else {
            asm volatile("s_waitcnt vmcnt(0)" ::: "memory");
        }
        __builtin_amdgcn_s_barrier();
        __builtin_amdgcn_sched_barrier(0);
        const char* bb = smem + cur * BUFA;
        // B fragments direct from global (L2-hot); latency hides under MFMAs
        half8 b[2][5];
#pragma unroll
        for (int fd = 0; fd < 2; ++fd)
#pragma unroll
            for (int t = 0; t < 5; ++t)
                b[fd][t] = *(const half8*)((const char*)Bw + (size_t)t * MATB + offBg[fd] + kt * 64);
        __builtin_amdgcn_s_setprio(1);
#pragma unroll
        for (int fm = 0; fm < 4; ++fm) {
            half8 hl = *(const half8*)(bb + offA[fm]);
            half8 hr = *(const half8*)(bb + (offA[fm] ^ 64));
            half8 hs = hl + hr;
#pragma unroll
            for (int fd = 0; fd < 2; ++fd) {
                acc[0][fm][fd] = __builtin_amdgcn_mfma_f32_16x16x32_f16(hs, b[fd][0], acc[0][fm][fd], 0, 0, 0);
                acc[1][fm][fd] = __builtin_amdgcn_mfma_f32_16x16x32_f16(hs, b[fd][1], acc[1][fm][fd], 0, 0, 0);
                acc[2][fm][fd] = __builtin_amdgcn_mfma_f32_16x16x32_f16(hs, b[fd][2], acc[2][fm][fd], 0, 0, 0);
                acc[3][fm][fd] = __builtin_amdgcn_mfma_f32_16x16x32_f16(hl, b[fd][3], acc[3][fm][fd], 0, 0, 0);
                acc[3][fm][fd] = __builtin_amdgcn_mfma_f32_16x16x32_f16(hr, b[fd][4], acc[3][fm][fd], 0, 0, 0);
                acc[4][fm][fd] = __builtin_amdgcn_mfma_f32_16x16x32_f16(hl, b[fd][4], acc[4][fm][fd], 0, 0, 0);
                acc[4][fm][fd] = __builtin_amdgcn_mfma_f32_16x16x32_f16(hr, b[fd][3], acc[4][fm][fd], 0, 0, 0);
            }
        }
        __builtin_amdgcn_s_setprio(0);
        if (kt + 1 < NT) __builtin_amdgcn_s_barrier();
        cur ^= 1;
    }

#pragma unroll
    for (int fd = 0; fd < 2; ++fd) {
        const int col = d0 + wd * 32 + fd * 16 + lr16;
        const float bi = biou[col];
        const float bo = biou[768 + col];
        const float bu = biou[1536 + col];
        const float bf = bfv[col];
#pragma unroll
        for (int fm = 0; fm < 4; ++fm) {
            const int rb = mBase + wm * 64 + fm * 16 + q * 4;
#pragma unroll
            for (int r4 = 0; r4 < 4; ++r4) {
                int row = rb + r4;
                if (row < M) {
                    float iv = acc[0][fm][fd][r4] + bi;
                    float ov = acc[1][fm][fd][r4] + bo;
                    float uv = acc[2][fm][fd][r4] + bu;
                    float fl = sigm(acc[3][fm][fd][r4] + bf);
                    float fr = sigm(acc[4][fm][fd][r4] + bf);
                    float clv = 0.f, crv = 0.f;
                    if (!firstLevel) {
                        clv = Cc[(size_t)(2 * row) * 768 + col];
                        crv = Cc[(size_t)(2 * row + 1) * 768 + col];
                    }
                    float c = sigm(iv) * tanhfast(uv) + fl * clv + fr * crv;
                    float h = sigm(ov) * tanhfast(c);
                    Hn[(size_t)row * 768 + col] = (_Float16)h;
                    Cn[(size_t)row * 768 + col] = c;
                }
            }
        }
    }
}

// ================= tree_small: tail levels (M=2048..8), per-level =================
__global__ __launch_bounds__(256, 3) void tree_small(
    const _Float16* __restrict__ Hc, const float* __restrict__ Cc,
    const _Float16* __restrict__ Bw,
    const float* __restrict__ biou, const float* __restrict__ bfv,
    _Float16* __restrict__ Hn, float* __restrict__ Cn,
    float* __restrict__ out,
    int M, int finalLevel)
{
    __shared__ __align__(16) char smem[2 * BUFT];
    const int tid = threadIdx.x;
    const int lane = tid & 63;
    const int w = tid >> 6;
    const int wm = w >> 1;
    const int wd = w & 1;
    const int bid = blockIdx.x;
    const int mb = bid / 24;
    const int d0c = bid - mb * 24;
    const int mBase = mb * 128;
    const int d0 = d0c * 32;

    const int l3 = lane >> 3, j = lane & 7;
    const int jj0 = j ^ l3;

    // A stage sources (4 slots), clamped
    unsigned offHa[4];
    int dstA[4];
#pragma unroll
    for (int s = 0; s < 4; ++s) {
        int u = s * 4 + w;
        int gr = mBase + u * 8 + l3;
        if (gr >= M) gr = M - 1;
        offHa[s] = (unsigned)(2 * gr + (jj0 >> 2)) * ROWB + (jj0 & 3) * 16;
        dstA[s] = u * 1024;
    }

#define STAGE_T(bi_, ko) do { \
    _Pragma("unroll") for (int s = 0; s < 4; ++s) \
        gload16((const char*)Hc + offHa[s] + (ko), smem + (bi_) * BUFT + dstA[s]); \
} while (0)

    const int q = lane >> 4;
    const int lr16 = lane & 15;
    int offA[4];
#pragma unroll
    for (int fm = 0; fm < 4; ++fm) {
        int r = wm * 64 + fm * 16 + lr16;
        offA[fm] = r * 128 + ((q ^ (r & 7)) * 16);
    }
    const int colOut = d0 + wd * 16 + lr16;
    const size_t offBg = (size_t)colOut * ROWB + q * 16;

    f32x4 acc[5][4];
#pragma unroll
    for (int g = 0; g < 5; ++g)
#pragma unroll
        for (int a = 0; a < 4; ++a)
            acc[g][a] = (f32x4){0.f, 0.f, 0.f, 0.f};

    STAGE_T(0, 0);
    int cur = 0;
    for (int kt = 0; kt < NT; ++kt) {
        if (kt + 1 < NT) {
            STAGE_T(cur ^ 1, (kt + 1) * 64);
            asm volatile("s_waitcnt vmcnt(4)" ::: "memory");
        } else {
            asm volatile("s_waitcnt vmcnt(0)" ::: "memory");
        }
        __builtin_amdgcn_s_barrier();
        __builtin_amdgcn_sched_barrier(0);
        const char* bb = smem + cur * BUFT;
        half8 b0 = *(const half8*)((const char*)Bw + 0 * (size_t)MATB + offBg + kt * 64);
        half8 b1 = *(const half8*)((const char*)Bw + 1 * (size_t)MATB + offBg + kt * 64);
        half8 b2 = *(const half8*)((const char*)Bw + 2 * (size_t)MATB + offBg + kt * 64);
        half8 b3 = *(const half8*)((const char*)Bw + 3 * (size_t)MATB + offBg + kt * 64);  // Wfp
        half8 b4 = *(const half8*)((const char*)Bw + 4 * (size_t)MATB + offBg + kt * 64);  // Wfh
        __builtin_amdgcn_s_setprio(1);
#pragma unroll
        for (int fm = 0; fm < 4; ++fm) {
            half8 hl = *(const half8*)(bb + offA[fm]);
            half8 hr = *(const half8*)(bb + (offA[fm] ^ 64));
            acc[3][fm] = __builtin_amdgcn_mfma_f32_16x16x32_f16(hl, b3, acc[3][fm], 0, 0, 0);
            acc[4][fm] = __builtin_amdgcn_mfma_f32_16x16x32_f16(hl, b4, acc[4][fm], 0, 0, 0);
            half8 hs = hl + hr;
            acc[0][fm] = __builtin_amdgcn_mfma_f32_16x16x32_f16(hs, b0, acc[0][fm], 0, 0, 0);
            acc[1][fm] = __builtin_amdgcn_mfma_f32_16x16x32_f16(hs, b1, acc[1][fm], 0, 0, 0);
            acc[2][fm] = __builtin_amdgcn_mfma_f32_16x16x32_f16(hs, b2, acc[2][fm], 0, 0, 0);
            acc[3][fm] = __builtin_amdgcn_mfma_f32_16x16x32_f16(hr, b4, acc[3][fm], 0, 0, 0);
            acc[4][fm] = __builtin_amdgcn_mfma_f32_16x16x32_f16(hr, b3, acc[4][fm], 0, 0, 0);
        }
        __builtin_amdgcn_s_setprio(0);
        if (kt + 1 < NT) __builtin_amdgcn_s_barrier();
        cur ^= 1;
    }

    const float bi = biou[colOut];
    const float bo = biou[768 + colOut];
    const float bu = biou[1536 + colOut];
    const float bf = bfv[colOut];
#pragma unroll
    for (int fm = 0; fm < 4; ++fm) {
        const int rb = mBase + wm * 64 + fm * 16 + q * 4;
#pragma unroll
        for (int r4 = 0; r4 < 4; ++r4) {
            int row = rb + r4;
            if (row < M) {
                float iv = acc[0][fm][r4] + bi;
                float ov = acc[1][fm][r4] + bo;
                float uv = acc[2][fm][r4] + bu;
                float fl = sigm(acc[3][fm][r4] + bf);
                float fr = sigm(acc[4][fm][r4] + bf);
                float clv = Cc[(size_t)(2 * row) * 768 + colOut];
                float crv = Cc[(size_t)(2 * row + 1) * 768 + colOut];
                float c = sigm(iv) * tanhfast(uv) + fl * clv + fr * crv;
                float h = sigm(ov) * tanhfast(c);
                if (finalLevel) {
                    out[row * 768 + colOut] = h;
                    out[6144 + row * 768 + colOut] = c;
                } else {
                    Hn[(size_t)row * 768 + colOut] = (_Float16)h;
                    Cn[(size_t)row * 768 + colOut] = c;
                }
            }
        }
    }
}

extern "C" void kernel_launch(void* const* d_in, const int* in_sizes, int n_in,
                              void* d_out, int out_size, void* d_ws, size_t ws_size,
                              hipStream_t stream)
{
    const float* leaf = (const float*)d_in[0];
    const float* Wiou = (const float*)d_in[1];
    const float* biou = (const float*)d_in[2];
    const float* Uiou = (const float*)d_in[3];
    const float* Wf   = (const float*)d_in[4];
    const float* bfv  = (const float*)d_in[5];
    const float* Uf   = (const float*)d_in[6];

    char* ws = (char*)d_ws;
    _Float16* Bw = (_Float16*)(ws);                  // 5x768x768 fp16 = 5,898,240 B
    _Float16* H0 = (_Float16*)(ws + 5898240);        // 65536x768 fp16
    _Float16* H1 = (_Float16*)(ws + 106561536);      // 32768x768 fp16
    float*    C0 = (float*)(ws + 156893184);         // 32768x768 f32
    float*    C1 = (float*)(ws + 257556480);         // 16384x768 f32

    prep_weights<<<1024, 256, 0, stream>>>(Wiou, Uiou, Wf, Uf, Bw);
    cast_leaves<<<2048, 256, 0, stream>>>(leaf, H0, 50331648 / 8);

    float* out = (float*)d_out;  // [2,8,768]
    _Float16* Hc = H0; _Float16* Hn = H1;
    float* Cc = C1; float* Cn = C0;
    int rows = 65536, level = 0;
    while (rows > 8) {
        int M = rows >> 1;
        if (M >= 4096) {
            int mblocks = M / 128;
            tree_level<<<mblocks * 12, 256, 0, stream>>>(Hc, Cc, Bw, biou, bfv,
                Hn, Cn, M, mblocks, level == 0 ? 1 : 0);
        } else {
            int mblocks = (M + 127) / 128;
            int fin = (M == 8) ? 1 : 0;
            tree_small<<<mblocks * 24, 256, 0, stream>>>(Hc, Cc, Bw, biou, bfv,
                Hn, Cn, out, M, fin);
        }
        _Float16* th = Hc; Hc = Hn; Hn = th;
        float* tc = Cc; Cc = Cn; Cn = tc;
        rows = M; ++level;
    }
}

// Round 14
// 927.252 us; speedup vs baseline: 2.2582x; 1.4922x over previous
//
#include <hip/hip_runtime.h>

// Child-Sum Tree-LSTM, level-synchronous, B=8 L=8192 D=768.
// Per level: 5 fused K=768 GEMM products + LSTM cell epilogue.
//   acc0..2 (i,o,u) = hs @ (0.5*W_iou + U_iou)^T
//   acc3 (fl-pre)   = hl@Wfp^T + hr@Wfh^T,  Wfp = 0.5*W_f + U_f, Wfh = 0.5*W_f
//   acc4 (fr-pre)   = hl@Wfh^T + hr@Wfp^T
// R14 = assembly of the two measured-best bodies, no new mechanisms:
//  Big levels (M>=4096): R4/R6 kernel A — 128x64 tile, 4 waves, B in LDS,
//    2 blocks/CU, 2-deep gload_lds pipeline, counted vmcnt(9), setprio,
//    mb-major bijective XCD order.            [measured: 347us @ level 0]
//  Tail levels (M=2048..8): R7 tree_small — 128x32 tile, 3 blocks/CU,
//    counted vmcnt(7).                        [measured-best at small M]
// Dead ends measured & abandoned: deeper pipelines (R3), phase splits
// (R6/R9), 3-block TLP at big M (R7), A- or B-direct-to-reg (R8/R13),
// 6-group algebra (R11), persistent/cooperative tail fusion (R10/R12).

typedef _Float16 half8 __attribute__((ext_vector_type(8)));
typedef float f32x4 __attribute__((ext_vector_type(4)));

#define ROWB 1536        // bytes per 768-elem fp16 row
#define NT 24            // 768 / 32
#define BUFA 36864       // kernel A buffer: A 16384 + B 20480
#define BUFT 26624       // tail buffer: A 16384 + B 10240

__device__ __forceinline__ float sigm(float x){ return 1.f/(1.f+__expf(-x)); }
__device__ __forceinline__ float tanhfast(float x){ return 1.f - 2.f/(1.f+__expf(2.f*x)); }

__device__ __forceinline__ void gload16(const void* g, void* l){
  __builtin_amdgcn_global_load_lds((const __attribute__((address_space(1))) void*)g,
                                   (__attribute__((address_space(3))) void*)l, 16, 0, 0);
}

// Bw: 5 mats of 768x768 fp16: [0..2]=0.5*W_iou+U_iou (i,o,u), [3]=Wfp=0.5Wf+Uf, [4]=Wfh=0.5Wf
__global__ void prep_weights(const float* __restrict__ Wiou, const float* __restrict__ Uiou,
                             const float* __restrict__ Wf, const float* __restrict__ Uf,
                             _Float16* __restrict__ Bw)
{
    const int n1 = 2304 * 768, n2 = n1 + 589824, n3 = n2 + 589824;
    int stride = gridDim.x * blockDim.x;
    for (int idx = blockIdx.x * blockDim.x + threadIdx.x; idx < n3; idx += stride) {
        float v;
        if (idx < n1)      v = __fmaf_rn(0.5f, Wiou[idx], Uiou[idx]);
        else if (idx < n2) { int k = idx - n1; v = __fmaf_rn(0.5f, Wf[k], Uf[k]); }
        else               { int k = idx - n2; v = 0.5f * Wf[k]; }
        Bw[idx] = (_Float16)v;
    }
}

__global__ void cast_leaves(const float* __restrict__ x, _Float16* __restrict__ h, int n8)
{
    int stride = gridDim.x * blockDim.x;
    for (int i = blockIdx.x * blockDim.x + threadIdx.x; i < n8; i += stride) {
        float4 v0 = ((const float4*)x)[2 * i];
        float4 v1 = ((const float4*)x)[2 * i + 1];
        half8 o = { (_Float16)v0.x, (_Float16)v0.y, (_Float16)v0.z, (_Float16)v0.w,
                    (_Float16)v1.x, (_Float16)v1.y, (_Float16)v1.z, (_Float16)v1.w };
        ((half8*)h)[i] = o;
    }
}

// ================= kernel A: big levels (M>=4096) — R4/R6 proven =================
// LDS per buffer: A 128 rows x 128B (row r chunk j: jj=j^(r&7), side=jj>>2,
// kchunk=jj&3 of H row 2*(mBase+r)+side); B at +16384: 5 mats x 32 pairs x
// 128B (pair p chunk j: jj=j^(p&7), col=d0+2p+(jj>>2), kchunk=jj&3).
__global__ __launch_bounds__(256, 2) void tree_level(
    const _Float16* __restrict__ Hc, const float* __restrict__ Cc,
    const _Float16* __restrict__ Bw,
    const float* __restrict__ biou, const float* __restrict__ bfv,
    _Float16* __restrict__ Hn, float* __restrict__ Cn,
    int M, int mblocks, int firstLevel)
{
    __shared__ __align__(16) char smem[2 * BUFA];
    const int tid = threadIdx.x;
    const int lane = tid & 63;
    const int w = tid >> 6;        // 0..3
    const int wm = w >> 1;         // 0..1 row-wave (64 rows)
    const int wd = w & 1;          // 0..1 col-wave (32 cols)

    // bijective XCD chunking; mb-major within XCD (H tile L2/L3-served)
    const int nwg = mblocks * 12;
    const int orig = blockIdx.x;
    const int xcd = orig & 7, qx = nwg >> 3, rx = nwg & 7;
    const int v = (xcd < rx ? xcd * (qx + 1) : rx * (qx + 1) + (xcd - rx) * qx) + (orig >> 3);
    const int mb = v / 12;
    const int d0c = v - mb * 12;
    const int mBase = mb * 128;
    const int d0 = d0c * 64;

    // stage sources: 4 A + 5 B per thread
    const int l3 = lane >> 3, j = lane & 7;
    const int jjA = j ^ l3;
    const int rbase = w * 8 + l3;
    unsigned offH[4];
#pragma unroll
    for (int s = 0; s < 4; ++s) {
        int gr = mBase + s * 32 + rbase;
        if (gr >= M) gr = M - 1;
        offH[s] = (unsigned)(2 * gr + (jjA >> 2)) * ROWB + (jjA & 3) * 16;
    }
    const int pB = w * 8 + l3;
    unsigned offWb[5];
#pragma unroll
    for (int t = 0; t < 5; ++t)
        offWb[t] = (unsigned)(t * 768 + d0 + 2 * pB + (jjA >> 2)) * ROWB + (jjA & 3) * 16;
    const int wK = w * 1024;

#define STAGE_A(bi, ko) do { \
    _Pragma("unroll") for (int s = 0; s < 4; ++s) \
        gload16((const char*)Hc + offH[s] + (ko), smem + (bi) * BUFA + s * 4096 + wK); \
    _Pragma("unroll") for (int t = 0; t < 5; ++t) \
        gload16((const char*)Bw + offWb[t] + (ko), smem + (bi) * BUFA + 16384 + t * 4096 + wK); \
} while (0)

    // compute offsets (kt-invariant)
    const int q = lane >> 4;
    const int lr16 = lane & 15;
    int offA[4], offB[2];
#pragma unroll
    for (int fm = 0; fm < 4; ++fm) {
        int r = wm * 64 + fm * 16 + lr16;
        offA[fm] = r * 128 + ((q ^ (r & 7)) * 16);
    }
#pragma unroll
    for (int fd = 0; fd < 2; ++fd) {
        int cl = wd * 32 + fd * 16 + lr16;
        int p = cl >> 1;
        int jb = ((cl & 1) * 4 + q) ^ (p & 7);
        offB[fd] = 16384 + p * 128 + jb * 16;
    }

    f32x4 acc[5][4][2];
#pragma unroll
    for (int g = 0; g < 5; ++g)
#pragma unroll
        for (int a = 0; a < 4; ++a)
#pragma unroll
            for (int b2 = 0; b2 < 2; ++b2)
                acc[g][a][b2] = (f32x4){0.f, 0.f, 0.f, 0.f};

    STAGE_A(0, 0);
    int cur = 0;
    for (int kt = 0; kt < NT; ++kt) {
        if (kt + 1 < NT) {
            STAGE_A(cur ^ 1, (kt + 1) * 64);
            asm volatile("s_waitcnt vmcnt(9)" ::: "memory");
        } else {
            asm volatile("s_waitcnt vmcnt(0)" ::: "memory");
        }
        __builtin_amdgcn_s_barrier();
        __builtin_amdgcn_sched_barrier(0);
        const char* bb = smem + cur * BUFA;
        half8 hl[4], hr[4];
#pragma unroll
        for (int fm = 0; fm < 4; ++fm) {
            hl[fm] = *(const half8*)(bb + offA[fm]);
            hr[fm] = *(const half8*)(bb + (offA[fm] ^ 64));
        }
        __builtin_amdgcn_s_setprio(1);
#pragma unroll
        for (int fd = 0; fd < 2; ++fd) {
            const char* bp = bb + offB[fd];
            half8 b0 = *(const half8*)(bp);
            half8 b1 = *(const half8*)(bp + 4096);
            half8 b2 = *(const half8*)(bp + 8192);
            half8 b3 = *(const half8*)(bp + 12288);   // Wfp
            half8 b4 = *(const half8*)(bp + 16384);   // Wfh
#pragma unroll
            for (int fm = 0; fm < 4; ++fm) {
                half8 hs = hl[fm] + hr[fm];
                acc[0][fm][fd] = __builtin_amdgcn_mfma_f32_16x16x32_f16(hs, b0, acc[0][fm][fd], 0, 0, 0);
                acc[1][fm][fd] = __builtin_amdgcn_mfma_f32_16x16x32_f16(hs, b1, acc[1][fm][fd], 0, 0, 0);
                acc[2][fm][fd] = __builtin_amdgcn_mfma_f32_16x16x32_f16(hs, b2, acc[2][fm][fd], 0, 0, 0);
                acc[3][fm][fd] = __builtin_amdgcn_mfma_f32_16x16x32_f16(hl[fm], b3, acc[3][fm][fd], 0, 0, 0);
                acc[3][fm][fd] = __builtin_amdgcn_mfma_f32_16x16x32_f16(hr[fm], b4, acc[3][fm][fd], 0, 0, 0);
                acc[4][fm][fd] = __builtin_amdgcn_mfma_f32_16x16x32_f16(hl[fm], b4, acc[4][fm][fd], 0, 0, 0);
                acc[4][fm][fd] = __builtin_amdgcn_mfma_f32_16x16x32_f16(hr[fm], b3, acc[4][fm][fd], 0, 0, 0);
            }
        }
        __builtin_amdgcn_s_setprio(0);
        if (kt + 1 < NT) __builtin_amdgcn_s_barrier();
        cur ^= 1;
    }

#pragma unroll
    for (int fd = 0; fd < 2; ++fd) {
        const int col = d0 + wd * 32 + fd * 16 + lr16;
        const float bi = biou[col];
        const float bo = biou[768 + col];
        const float bu = biou[1536 + col];
        const float bf = bfv[col];
#pragma unroll
        for (int fm = 0; fm < 4; ++fm) {
            const int rb = mBase + wm * 64 + fm * 16 + q * 4;
#pragma unroll
            for (int r4 = 0; r4 < 4; ++r4) {
                int row = rb + r4;
                if (row < M) {
                    float iv = acc[0][fm][fd][r4] + bi;
                    float ov = acc[1][fm][fd][r4] + bo;
                    float uv = acc[2][fm][fd][r4] + bu;
                    float fl = sigm(acc[3][fm][fd][r4] + bf);
                    float fr = sigm(acc[4][fm][fd][r4] + bf);
                    float clv = 0.f, crv = 0.f;
                    if (!firstLevel) {
                        clv = Cc[(size_t)(2 * row) * 768 + col];
                        crv = Cc[(size_t)(2 * row + 1) * 768 + col];
                    }
                    float c = sigm(iv) * tanhfast(uv) + fl * clv + fr * crv;
                    float h = sigm(ov) * tanhfast(c);
                    Hn[(size_t)row * 768 + col] = (_Float16)h;
                    Cn[(size_t)row * 768 + col] = c;
                }
            }
        }
    }
}

// ================= tree_small: tail levels (M=2048..8) — R7 proven =================
__global__ __launch_bounds__(256, 3) void tree_small(
    const _Float16* __restrict__ Hc, const float* __restrict__ Cc,
    const _Float16* __restrict__ Bw,
    const float* __restrict__ biou, const float* __restrict__ bfv,
    _Float16* __restrict__ Hn, float* __restrict__ Cn,
    float* __restrict__ out,
    int M, int finalLevel)
{
    __shared__ __align__(16) char smem[2 * BUFT];
    const int tid = threadIdx.x;
    const int lane = tid & 63;
    const int w = tid >> 6;
    const int wm = w >> 1;
    const int wd = w & 1;
    const int bid = blockIdx.x;
    const int mb = bid / 24;
    const int d0c = bid - mb * 24;
    const int mBase = mb * 128;
    const int d0 = d0c * 32;

    const int l3 = lane >> 3, j = lane & 7;
    const int jj0 = j ^ l3;

    // A stage sources (4 slots), clamped; B sources (3 slots, dup trick)
    unsigned offHa[4];
    int dstA[4];
#pragma unroll
    for (int s = 0; s < 4; ++s) {
        int u = s * 4 + w;
        int gr = mBase + u * 8 + l3;
        if (gr >= M) gr = M - 1;
        offHa[s] = (unsigned)(2 * gr + (jj0 >> 2)) * ROWB + (jj0 & 3) * 16;
        dstA[s] = u * 1024;
    }
    unsigned offWb[3];
    int dstB[3];
#pragma unroll
    for (int s = 0; s < 3; ++s) {
        int i = s * 4 + w;
        if (i >= 10) i -= 2;
        int t = i >> 1, half = i & 1;
        int p = half * 8 + l3;
        offWb[s] = (unsigned)(t * 768 + d0 + 2 * p + (jj0 >> 2)) * ROWB + (jj0 & 3) * 16;
        dstB[s] = 16384 + t * 2048 + half * 1024;
    }

#define STAGE_T(bi_, ko) do { \
    _Pragma("unroll") for (int s = 0; s < 4; ++s) \
        gload16((const char*)Hc + offHa[s] + (ko), smem + (bi_) * BUFT + dstA[s]); \
    _Pragma("unroll") for (int s = 0; s < 3; ++s) \
        gload16((const char*)Bw + offWb[s] + (ko), smem + (bi_) * BUFT + dstB[s]); \
} while (0)

    const int q = lane >> 4;
    const int lr16 = lane & 15;
    int offA[4];
#pragma unroll
    for (int fm = 0; fm < 4; ++fm) {
        int r = wm * 64 + fm * 16 + lr16;
        offA[fm] = r * 128 + ((q ^ (r & 7)) * 16);
    }
    int offB;
    {
        int cl = wd * 16 + lr16;
        int p = cl >> 1;
        int jb = ((cl & 1) * 4 + q) ^ (p & 7);
        offB = 16384 + p * 128 + jb * 16;
    }

    f32x4 acc[5][4];
#pragma unroll
    for (int g = 0; g < 5; ++g)
#pragma unroll
        for (int a = 0; a < 4; ++a)
            acc[g][a] = (f32x4){0.f, 0.f, 0.f, 0.f};

    STAGE_T(0, 0);
    int cur = 0;
    for (int kt = 0; kt < NT; ++kt) {
        if (kt + 1 < NT) {
            STAGE_T(cur ^ 1, (kt + 1) * 64);
            asm volatile("s_waitcnt vmcnt(7)" ::: "memory");
        } else {
            asm volatile("s_waitcnt vmcnt(0)" ::: "memory");
        }
        __builtin_amdgcn_s_barrier();
        __builtin_amdgcn_sched_barrier(0);
        const char* bb = smem + cur * BUFT;
        half8 b0 = *(const half8*)(bb + offB);
        half8 b1 = *(const half8*)(bb + offB + 2048);
        half8 b2 = *(const half8*)(bb + offB + 4096);
        half8 b3 = *(const half8*)(bb + offB + 6144);   // Wfp
        half8 b4 = *(const half8*)(bb + offB + 8192);   // Wfh
        __builtin_amdgcn_s_setprio(1);
#pragma unroll
        for (int fm = 0; fm < 4; ++fm) {
            half8 hl = *(const half8*)(bb + offA[fm]);
            half8 hr = *(const half8*)(bb + (offA[fm] ^ 64));
            acc[3][fm] = __builtin_amdgcn_mfma_f32_16x16x32_f16(hl, b3, acc[3][fm], 0, 0, 0);
            acc[4][fm] = __builtin_amdgcn_mfma_f32_16x16x32_f16(hl, b4, acc[4][fm], 0, 0, 0);
            half8 hs = hl + hr;
            acc[0][fm] = __builtin_amdgcn_mfma_f32_16x16x32_f16(hs, b0, acc[0][fm], 0, 0, 0);
            acc[1][fm] = __builtin_amdgcn_mfma_f32_16x16x32_f16(hs, b1, acc[1][fm], 0, 0, 0);
            acc[2][fm] = __builtin_amdgcn_mfma_f32_16x16x32_f16(hs, b2, acc[2][fm], 0, 0, 0);
            acc[3][fm] = __builtin_amdgcn_mfma_f32_16x16x32_f16(hr, b4, acc[3][fm], 0, 0, 0);
            acc[4][fm] = __builtin_amdgcn_mfma_f32_16x16x32_f16(hr, b3, acc[4][fm], 0, 0, 0);
        }
        __builtin_amdgcn_s_setprio(0);
        if (kt + 1 < NT) __builtin_amdgcn_s_barrier();
        cur ^= 1;
    }

    const int col = d0 + wd * 16 + lr16;
    const float bi = biou[col];
    const float bo = biou[768 + col];
    const float bu = biou[1536 + col];
    const float bf = bfv[col];
#pragma unroll
    for (int fm = 0; fm < 4; ++fm) {
        const int rb = mBase + wm * 64 + fm * 16 + q * 4;
#pragma unroll
        for (int r4 = 0; r4 < 4; ++r4) {
            int row = rb + r4;
            if (row < M) {
                float iv = acc[0][fm][r4] + bi;
                float ov = acc[1][fm][r4] + bo;
                float uv = acc[2][fm][r4] + bu;
                float fl = sigm(acc[3][fm][r4] + bf);
                float fr = sigm(acc[4][fm][r4] + bf);
                float clv = Cc[(size_t)(2 * row) * 768 + col];
                float crv = Cc[(size_t)(2 * row + 1) * 768 + col];
                float c = sigm(iv) * tanhfast(uv) + fl * clv + fr * crv;
                float h = sigm(ov) * tanhfast(c);
                if (finalLevel) {
                    out[row * 768 + col] = h;
                    out[6144 + row * 768 + col] = c;
                } else {
                    Hn[(size_t)row * 768 + col] = (_Float16)h;
                    Cn[(size_t)row * 768 + col] = c;
                }
            }
        }
    }
}

extern "C" void kernel_launch(void* const* d_in, const int* in_sizes, int n_in,
                              void* d_out, int out_size, void* d_ws, size_t ws_size,
                              hipStream_t stream)
{
    const float* leaf = (const float*)d_in[0];
    const float* Wiou = (const float*)d_in[1];
    const float* biou = (const float*)d_in[2];
    const float* Uiou = (const float*)d_in[3];
    const float* Wf   = (const float*)d_in[4];
    const float* bfv  = (const float*)d_in[5];
    const float* Uf   = (const float*)d_in[6];

    char* ws = (char*)d_ws;
    _Float16* Bw = (_Float16*)(ws);                  // 5x768x768 fp16 = 5,898,240 B
    _Float16* H0 = (_Float16*)(ws + 5898240);        // 65536x768 fp16
    _Float16* H1 = (_Float16*)(ws + 106561536);      // 32768x768 fp16
    float*    C0 = (float*)(ws + 156893184);         // 32768x768 f32
    float*    C1 = (float*)(ws + 257556480);         // 16384x768 f32

    prep_weights<<<1024, 256, 0, stream>>>(Wiou, Uiou, Wf, Uf, Bw);
    cast_leaves<<<2048, 256, 0, stream>>>(leaf, H0, 50331648 / 8);

    float* out = (float*)d_out;  // [2,8,768]
    _Float16* Hc = H0; _Float16* Hn = H1;
    float* Cc = C1; float* Cn = C0;
    int rows = 65536, level = 0;
    while (rows > 8) {
        int M = rows >> 1;
        if (M >= 4096) {
            int mblocks = M / 128;
            tree_level<<<mblocks * 12, 256, 0, stream>>>(Hc, Cc, Bw, biou, bfv,
                Hn, Cn, M, mblocks, level == 0 ? 1 : 0);
        } else {
            int mblocks = (M + 127) / 128;
            int fin = (M == 8) ? 1 : 0;
            tree_small<<<mblocks * 24, 256, 0, stream>>>(Hc, Cc, Bw, biou, bfv,
                Hn, Cn, out, M, fin);
        }
        _Float16* th = Hc; Hc = Hn; Hn = th;
        float* tc = Cc; Cc = Cn; Cn = tc;
        rows = M; ++level;
    }
}